// Round 3
// baseline (237.445 us; speedup 1.0000x reference)
//
#include <hip/hip_runtime.h>
#include <math.h>

#define SMK    2048
#define TAPS   32
#define OUTLEN (SMK + TAPS - 1)   // 2079
#define PAD    32
#define SLOTS  (PAD + SMK + PAD)  // 2112 float2 slots, LINEAR layout (16.9 KB)
#define MDFT   64

__device__ __forceinline__ float rfl(float x) {
    return __int_as_float(__builtin_amdgcn_readfirstlane(__float_as_int(x)));
}

__global__ __launch_bounds__(256, 4)
void conv_kernel(const float* __restrict__ input,
                 const float* __restrict__ cof,
                 float* __restrict__ out0,
                 float* __restrict__ out1)
{
    __shared__ float2 s_sig[SLOTS];
    __shared__ float2 s_tw[MDFT];

    const int tid = threadIdx.x;
    const int row = blockIdx.x;

    // ---- taps -> SGPR (block-uniform values via readfirstlane) ----
    const float2* __restrict__ ct = (const float2*)(cof + (size_t)row * (TAPS * 2));
    float hre[TAPS], him[TAPS];
    #pragma unroll
    for (int l = 0; l < TAPS; ++l) {
        float2 tv = ct[l];               // wave-uniform address
        hre[l] = rfl(tv.x);
        him[l] = rfl(tv.y);
    }

    // ---- stage signal row (16 KB) into LINEAR LDS ----
    const float4* gin = (const float4*)(input + (size_t)row * SMK * 2);
    float4* s4 = (float4*)s_sig;         // one float4 = 2 float2 slots
    float4 stg[4];
    #pragma unroll
    for (int k = 0; k < 4; ++k) stg[k] = gin[tid + 256 * k];
    #pragma unroll
    for (int k = 0; k < 4; ++k) s4[(PAD / 2) + tid + 256 * k] = stg[k];

    // zero pads: front slots [0,32), back slots [2080,2112)
    if (tid < PAD) {
        s_sig[tid] = make_float2(0.f, 0.f);
    } else if (tid < 2 * PAD) {
        s_sig[SMK + tid] = make_float2(0.f, 0.f);   // 2080..2111
    }
    // twiddles e^{-2 pi i j / 64}, built by wave 1 (the DFT wave)
    if (tid >= 64 && tid < 128) {
        int j = tid - 64;
        float sv, cv;
        __sincosf(-2.0f * (float)M_PI * (float)j / (float)MDFT, &sv, &cv);
        s_tw[j] = make_float2(cv, sv);
    }
    __syncthreads();

    float2* go2 = (float2*)(out0 + (size_t)row * OUTLEN * 2);

    // ---- main: 4 groups of 2 consecutive outputs, t = 2*tid + 512*j ----
    #pragma unroll 1
    for (int j = 0; j < 4; ++j) {
        const int t0 = 2 * tid + 512 * j;
        // window slots [t0-32, t0+2) -> float4 index (t0-32+PAD)/2 = t0/2
        const float4* base = s4 + (t0 >> 1);
        float4 w4[17];                    // single base + offset: immediates
        #pragma unroll
        for (int i = 0; i < 17; ++i) w4[i] = base[i];

        float a0x = 0.f, a0y = 0.f, a1x = 0.f, a1y = 0.f;
        #pragma unroll
        for (int l = 0; l < TAPS; ++l) {
            const float hr = hre[l];
            const float hi = him[l];
            {   // k = 0: window float2 index m = 32 - l (1..32)
                const int m = 32 - l;
                const float sx = (m & 1) ? w4[m >> 1].z : w4[m >> 1].x;
                const float sy = (m & 1) ? w4[m >> 1].w : w4[m >> 1].y;
                a0x = fmaf(sx, hr, fmaf(-sy, hi, a0x));
                a0y = fmaf(sx, hi, fmaf( sy, hr, a0y));
            }
            {   // k = 1: m = 33 - l (2..33)
                const int m = 33 - l;
                const float sx = (m & 1) ? w4[m >> 1].z : w4[m >> 1].x;
                const float sy = (m & 1) ? w4[m >> 1].w : w4[m >> 1].y;
                a1x = fmaf(sx, hr, fmaf(-sy, hi, a1x));
                a1y = fmaf(sx, hi, fmaf( sy, hr, a1y));
            }
        }
        go2[t0]     = make_float2(a0x, a0y);
        go2[t0 + 1] = make_float2(a1x, a1y);
    }

    // ---- wave 1: fused 64-pt DFT of zero-padded taps ----
    if (tid >= 64 && tid < 128) {
        const int k = tid - 64;
        float ax = 0.f, ay = 0.f;
        #pragma unroll
        for (int l = 0; l < TAPS; ++l) {
            float2 w = s_tw[(k * l) & (MDFT - 1)];
            ax = fmaf(w.x, hre[l], fmaf(-w.y, him[l], ax));
            ay = fmaf(w.y, hre[l], fmaf( w.x, him[l], ay));
        }
        ((float2*)out1)[(size_t)row * MDFT + k] = make_float2(ax, ay);
    }
    // ---- wave 2: tail outputs t = 2048..2078 ----
    else if (tid >= 128 && tid < 128 + (OUTLEN - SMK)) {
        const int t = SMK + (tid - 128);
        float ax = 0.f, ay = 0.f;
        #pragma unroll
        for (int l = 0; l < TAPS; ++l) {
            float2 s = s_sig[PAD + t - l];   // back pad supplies zeros
            ax = fmaf(s.x, hre[l], fmaf(-s.y, him[l], ax));
            ay = fmaf(s.x, him[l], fmaf( s.y, hre[l], ay));
        }
        go2[t] = make_float2(ax, ay);
    }
}

extern "C" void kernel_launch(void* const* d_in, const int* in_sizes, int n_in,
                              void* d_out, int out_size, void* d_ws, size_t ws_size,
                              hipStream_t stream)
{
    const float* input = (const float*)d_in[0];  // (N,P,2048,2) fp32
    const float* cof   = (const float*)d_in[1];  // (N,P,32,2)   fp32
    // d_in[2] is M (=64), compile-time here.

    const int NP = in_sizes[0] / (SMK * 2);      // 16384

    float* out0 = (float*)d_out;                           // (NP, 2079, 2)
    float* out1 = out0 + (size_t)NP * OUTLEN * 2;          // (NP, 64, 2)

    conv_kernel<<<NP, 256, 0, stream>>>(input, cof, out0, out1);
}

// Round 4
// 203.962 us; speedup vs baseline: 1.1642x; 1.1642x over previous
//
#include <hip/hip_runtime.h>
#include <math.h>

#define SMK    2048
#define TAPS   32
#define OUTLEN (SMK + TAPS - 1)   // 2079
#define PAD    32
#define SLOTS  (PAD + SMK + PAD)  // 2112 float2 slots, LINEAR (16.9 KB)
#define MDFT   64
#define ROWS_PER_BLOCK 8
#define NBLOCKS 2048

__device__ __forceinline__ float rfl(float x) {
    return __int_as_float(__builtin_amdgcn_readfirstlane(__float_as_int(x)));
}

__global__ __launch_bounds__(256)
__attribute__((amdgpu_waves_per_eu(4, 4)))
void conv_kernel(const float* __restrict__ input,
                 const float* __restrict__ cof,
                 float* __restrict__ out0,
                 float* __restrict__ out1)
{
    __shared__ float2 s_sig[SLOTS];
    __shared__ float2 s_tw[MDFT];

    const int tid = threadIdx.x;
    float4* s4 = (float4*)s_sig;

    // One-time per block: zero pads (never overwritten) + DFT twiddles.
    if (tid < PAD) {
        s_sig[tid] = make_float2(0.f, 0.f);                 // front pad [0,32)
    } else if (tid < 2 * PAD) {
        s_sig[SMK + tid] = make_float2(0.f, 0.f);           // back pad [2080,2112)
    }
    if (tid >= 64 && tid < 128) {
        int j = tid - 64;
        float sv, cv;
        __sincosf(-2.0f * (float)M_PI * (float)j / (float)MDFT, &sv, &cv);
        s_tw[j] = make_float2(cv, sv);
    }

    // Preload row 0's signal into registers (16 VGPR).
    float4 stg[4];
    {
        const float4* gin = (const float4*)(input + (size_t)blockIdx.x * SMK * 2);
        #pragma unroll
        for (int k2 = 0; k2 < 4; ++k2) stg[k2] = gin[tid + 256 * k2];
    }

    #pragma unroll 1
    for (int it = 0; it < ROWS_PER_BLOCK; ++it) {
        const int r = blockIdx.x + NBLOCKS * it;

        // Taps -> SGPR (uniform loads; latency hidden under barriers below).
        const float2* __restrict__ ct = (const float2*)(cof + (size_t)r * (TAPS * 2));
        float hre[TAPS], him[TAPS];
        #pragma unroll
        for (int l = 0; l < TAPS; ++l) {
            float2 tv = ct[l];
            hre[l] = rfl(tv.x);
            him[l] = rfl(tv.y);
        }

        __syncthreads();   // previous row's LDS reads complete
        #pragma unroll
        for (int k2 = 0; k2 < 4; ++k2) s4[(PAD / 2) + tid + 256 * k2] = stg[k2];

        // Issue next row's loads now; they fly under the barrier + compute.
        if (it + 1 < ROWS_PER_BLOCK) {
            const float4* gn = (const float4*)(input + (size_t)(r + NBLOCKS) * SMK * 2);
            #pragma unroll
            for (int k2 = 0; k2 < 4; ++k2) stg[k2] = gn[tid + 256 * k2];
        }
        __syncthreads();   // row r visible in LDS

        float2* go2 = (float2*)(out0 + (size_t)r * OUTLEN * 2);

        // ---- main: 8 consecutive outputs t0..t0+7, K-split into 4 tap chunks ----
        const int t0 = 8 * tid;
        float2 acc[8];
        #pragma unroll
        for (int k = 0; k < 8; ++k) acc[k] = make_float2(0.f, 0.f);

        #pragma unroll
        for (int c = 0; c < 4; ++c) {
            // chunk c covers taps l = 8c..8c+7; window = 8 float4 from one base
            const float4* base = s4 + (4 * tid + 12 - 4 * c);
            float4 w[8];
            #pragma unroll
            for (int i = 0; i < 8; ++i) w[i] = base[i];

            #pragma unroll
            for (int lp = 0; lp < 8; ++lp) {
                const float hr = hre[8 * c + lp];
                const float hi = him[8 * c + lp];
                #pragma unroll
                for (int k = 0; k < 8; ++k) {
                    const int m = 8 + k - lp;            // 1..15, compile-time
                    const float sx = (m & 1) ? w[m >> 1].z : w[m >> 1].x;
                    const float sy = (m & 1) ? w[m >> 1].w : w[m >> 1].y;
                    // pk_fma-friendly pairing: (acc.x, acc.y) += (sx,sx)*(hr,hi)
                    acc[k].x = fmaf(sx, hr, acc[k].x);
                    acc[k].y = fmaf(sx, hi, acc[k].y);
                    // (acc.x, acc.y) += (sy,sy)*(-hi,hr)
                    acc[k].x = fmaf(sy, -hi, acc[k].x);
                    acc[k].y = fmaf(sy,  hr, acc[k].y);
                }
            }
        }
        #pragma unroll
        for (int k = 0; k < 8; ++k) go2[t0 + k] = acc[k];

        // ---- wave 1: fused 64-pt DFT of zero-padded taps ----
        if (tid >= 64 && tid < 128) {
            const int kk = tid - 64;
            float ax = 0.f, ay = 0.f;
            #pragma unroll
            for (int l = 0; l < TAPS; ++l) {
                float2 w = s_tw[(kk * l) & (MDFT - 1)];
                ax = fmaf(w.x, hre[l], fmaf(-w.y, him[l], ax));
                ay = fmaf(w.y, hre[l], fmaf( w.x, him[l], ay));
            }
            ((float2*)out1)[(size_t)r * MDFT + kk] = make_float2(ax, ay);
        }
        // ---- wave 2: tail outputs t = 2048..2078 ----
        else if (tid >= 128 && tid < 128 + (OUTLEN - SMK)) {
            const int t = SMK + (tid - 128);
            float ax = 0.f, ay = 0.f;
            #pragma unroll
            for (int l = 0; l < TAPS; ++l) {
                float2 s = s_sig[PAD + t - l];   // back pad supplies zeros
                ax = fmaf(s.x, hre[l], fmaf(-s.y, him[l], ax));
                ay = fmaf(s.x, him[l], fmaf( s.y, hre[l], ay));
            }
            go2[t] = make_float2(ax, ay);
        }
    }
}

extern "C" void kernel_launch(void* const* d_in, const int* in_sizes, int n_in,
                              void* d_out, int out_size, void* d_ws, size_t ws_size,
                              hipStream_t stream)
{
    const float* input = (const float*)d_in[0];  // (N,P,2048,2) fp32
    const float* cof   = (const float*)d_in[1];  // (N,P,32,2)   fp32
    // d_in[2] is M (=64), compile-time here.

    float* out0 = (float*)d_out;                                   // (NP, 2079, 2)
    const int NP = in_sizes[0] / (SMK * 2);                        // 16384
    float* out1 = out0 + (size_t)NP * OUTLEN * 2;                  // (NP, 64, 2)

    conv_kernel<<<NBLOCKS, 256, 0, stream>>>(input, cof, out0, out1);
}